// Round 5
// baseline (257.858 us; speedup 1.0000x reference)
//
#include <hip/hip_runtime.h>

#define DIM 128

typedef __attribute__((ext_vector_type(2))) _Float16 f16x2;
typedef __attribute__((ext_vector_type(4))) _Float16 f16x4;
typedef __attribute__((ext_vector_type(8))) _Float16 f16x8;
typedef __attribute__((ext_vector_type(4))) float f32x4;

// ---------------------------------------------------------------------------
// k_pre: fused degree-count + x->f16 convert + W transpose/convert.
// Block ranges: [0,bx) cvt-x, [bx,bx+be) count, [bx+be,bx+be+bw) cvt-w.
// ---------------------------------------------------------------------------
__global__ __launch_bounds__(256) void k_pre(const float* __restrict__ x,
                                             _Float16* __restrict__ xh, int n4,
                                             int bx,
                                             const int* __restrict__ dst,
                                             int* __restrict__ deg, int E,
                                             int be,
                                             const float* __restrict__ W1l,
                                             const float* __restrict__ W1r,
                                             _Float16* __restrict__ Wt) {
  int bid = blockIdx.x;
  if (bid < bx) {
    int i = bid * 256 + threadIdx.x;
    if (i < n4) {
      float4 v = ((const float4*)x)[i];
      f16x4 o;
      o.x = (_Float16)v.x; o.y = (_Float16)v.y;
      o.z = (_Float16)v.z; o.w = (_Float16)v.w;
      ((f16x4*)xh)[i] = o;
    }
  } else if (bid < bx + be) {
    int e = (bid - bx) * 256 + threadIdx.x;
    if (e < E) atomicAdd(&deg[dst[e]], 1);
  } else {
    int idx = (bid - bx - be) * 256 + threadIdx.x;  // 32768 total
    if (idx < 128 * 256) {
      int nn = idx >> 8, k = idx & 255;
      float v = (k < 128) ? W1l[(size_t)k * 128 + nn]
                          : W1r[(size_t)(k - 128) * 128 + nn];
      Wt[(size_t)nn * 256 + k] = (_Float16)v;
    }
  }
}

// ---------------------------------------------------------------------------
// Scan phase 1: per-block (256-elem) sums.
// ---------------------------------------------------------------------------
__global__ __launch_bounds__(256) void k_scan1(const int* __restrict__ deg,
                                               int* __restrict__ part, int n) {
  __shared__ int red[256];
  int t = threadIdx.x;
  int i = blockIdx.x * 256 + t;
  red[t] = (i < n) ? deg[i] : 0;
  __syncthreads();
  for (int off = 128; off > 0; off >>= 1) {
    if (t < off) red[t] += red[t + off];
    __syncthreads();
  }
  if (t == 0) part[blockIdx.x] = red[0];
}

// ---------------------------------------------------------------------------
// Scan phase 2+3 fused: every block scans the <=256 partials in LDS
// (redundantly), takes its own exclusive offset, then scans its 256-chunk.
// cursor aliases deg (each thread reads deg[i] before cursor write; safe).
// ---------------------------------------------------------------------------
__global__ __launch_bounds__(256) void k_scan23(const int* __restrict__ deg,
                                                const int* __restrict__ part,
                                                int npart,
                                                int* __restrict__ rowptr,
                                                int* __restrict__ cursor,
                                                int n, int E) {
  __shared__ int ps[256];
  __shared__ int ls[256];
  int t = threadIdx.x;
  ps[t] = (t < npart) ? part[t] : 0;
  __syncthreads();
  for (int off = 1; off < 256; off <<= 1) {
    int u = (t >= off) ? ps[t - off] : 0;
    __syncthreads();
    ps[t] += u;
    __syncthreads();
  }
  int blockOff = (blockIdx.x == 0) ? 0 : ps[blockIdx.x - 1];

  int i = blockIdx.x * 256 + t;
  int v = (i < n) ? deg[i] : 0;
  ls[t] = v;
  __syncthreads();
  for (int off = 1; off < 256; off <<= 1) {
    int u = (t >= off) ? ls[t - off] : 0;
    __syncthreads();
    ls[t] += u;
    __syncthreads();
  }
  int excl = ls[t] - v + blockOff;
  if (i < n) {
    rowptr[i] = excl;
    cursor[i] = excl;
  }
  if (i == 0) rowptr[n] = E;
}

__global__ __launch_bounds__(256) void k_fill(const int* __restrict__ src,
                                              const int* __restrict__ dst,
                                              int* __restrict__ cursor,
                                              int* __restrict__ col, int E) {
  int e = blockIdx.x * 256 + threadIdx.x;
  if (e < E) {
    int p = atomicAdd(&cursor[dst[e]], 1);
    col[p] = src[e];
  }
}

// ---------------------------------------------------------------------------
// Fused aggregation + MFMA GEMM + epilogue (agg & h never hit HBM):
//   agg = mean_{CSR} xh  (gathered into padded LDS tile)
//   h = relu([agg|x] @ [W1l;W1r] + b1);  s = h.w2l;  t = h.w2r
// Block: 64 nodes x 128 cols, 4 waves.
// Gather: wave wv computes nodes wv*16..+15, lane = 2 cols (f16x2).
// MFMA: 2x2 wave split (row-half x col-half); wave = 2 row-tiles x 4
// col-tiles, K=256 in 8 steps of mfma_f32_16x16x32_f16.
// LDS A-tile padded to 136 f16/row -> 2-way bank aliasing only (free).
// ---------------------------------------------------------------------------
__global__ __launch_bounds__(256) void k_gemm(const _Float16* __restrict__ xh,
                                              const int* __restrict__ rowptr,
                                              const int* __restrict__ col,
                                              const _Float16* __restrict__ Wt,
                                              const float* __restrict__ b1,
                                              const float* __restrict__ w2l,
                                              const float* __restrict__ w2r,
                                              float* __restrict__ sbuf,
                                              float* __restrict__ tbuf, int n) {
  __shared__ _Float16 s_a[64][136];
  __shared__ float s_l[64], t_l[64];
  int tid = threadIdx.x;
  int wv = tid >> 6;
  int lane = tid & 63;
  int q = lane >> 4;
  int l16 = lane & 15;
  int nb = blockIdx.x * 64;

  if (tid < 64) { s_l[tid] = 0.f; t_l[tid] = 0.f; }

  const f16x2* X2 = (const f16x2*)xh;
  // ---- gather phase: 16 nodes per wave ----
  for (int ln = 0; ln < 16; ++ln) {
    int row = wv * 16 + ln;
    int node = nb + row;
    float ax0 = 0.f, ay0 = 0.f, ax1 = 0.f, ay1 = 0.f;
    float ax2 = 0.f, ay2 = 0.f, ax3 = 0.f, ay3 = 0.f;
    float inv = 0.f;
    if (node < n) {
      int b = rowptr[node], e = rowptr[node + 1];
      int i = b;
      for (; i + 4 <= e; i += 4) {
        int c0 = col[i], c1 = col[i + 1], c2 = col[i + 2], c3 = col[i + 3];
        f16x2 v0 = X2[(size_t)c0 * 64 + lane];
        f16x2 v1 = X2[(size_t)c1 * 64 + lane];
        f16x2 v2 = X2[(size_t)c2 * 64 + lane];
        f16x2 v3 = X2[(size_t)c3 * 64 + lane];
        ax0 += (float)v0.x; ay0 += (float)v0.y;
        ax1 += (float)v1.x; ay1 += (float)v1.y;
        ax2 += (float)v2.x; ay2 += (float)v2.y;
        ax3 += (float)v3.x; ay3 += (float)v3.y;
      }
      for (; i < e; ++i) {
        f16x2 v = X2[(size_t)col[i] * 64 + lane];
        ax0 += (float)v.x; ay0 += (float)v.y;
      }
      inv = 1.0f / (float)max(e - b, 1);
    }
    f16x2 o;
    o.x = (_Float16)((ax0 + ax1 + ax2 + ax3) * inv);
    o.y = (_Float16)((ay0 + ay1 + ay2 + ay3) * inv);
    *(f16x2*)&s_a[row][lane * 2] = o;
  }
  __syncthreads();

  // ---- MFMA phase ----
  int rh = wv & 1;   // row-half
  int ch = wv >> 1;  // col-half
  f32x4 acc[2][4];
#pragma unroll
  for (int rt = 0; rt < 2; ++rt)
#pragma unroll
    for (int ct = 0; ct < 4; ++ct) acc[rt][ct] = (f32x4){0.f, 0.f, 0.f, 0.f};

  const _Float16* alds[2];
  const _Float16* arow1[2];
#pragma unroll
  for (int rt = 0; rt < 2; ++rt) {
    int row = rh * 32 + rt * 16 + l16;
    alds[rt] = &s_a[row][q * 8];
    int r = nb + row;
    if (r > n - 1) r = n - 1;
    arow1[rt] = xh + (size_t)r * 128 + q * 8;
  }
  const _Float16* bp[4];
#pragma unroll
  for (int ct = 0; ct < 4; ++ct)
    bp[ct] = Wt + (size_t)(ch * 64 + ct * 16 + l16) * 256 + q * 8;

#pragma unroll
  for (int s = 0; s < 8; ++s) {
    f16x8 a[2], b[4];
#pragma unroll
    for (int rt = 0; rt < 2; ++rt)
      a[rt] = (s < 4) ? *(const f16x8*)(alds[rt] + s * 32)
                      : *(const f16x8*)(arow1[rt] + (s - 4) * 32);
#pragma unroll
    for (int ct = 0; ct < 4; ++ct) b[ct] = *(const f16x8*)(bp[ct] + s * 32);
#pragma unroll
    for (int rt = 0; rt < 2; ++rt)
#pragma unroll
      for (int ct = 0; ct < 4; ++ct)
        acc[rt][ct] = __builtin_amdgcn_mfma_f32_16x16x32_f16(a[rt], b[ct],
                                                             acc[rt][ct], 0, 0, 0);
  }

  float bia[4], wl[4], wr[4];
#pragma unroll
  for (int ct = 0; ct < 4; ++ct) {
    int c = ch * 64 + ct * 16 + l16;
    bia[ct] = b1[c];
    wl[ct] = w2l[c];
    wr[ct] = w2r[c];
  }

#pragma unroll
  for (int rt = 0; rt < 2; ++rt) {
#pragma unroll
    for (int r = 0; r < 4; ++r) {
      float sp = 0.f, tp = 0.f;
#pragma unroll
      for (int ct = 0; ct < 4; ++ct) {
        float h = fmaxf(acc[rt][ct][r] + bia[ct], 0.f);
        sp += h * wl[ct];
        tp += h * wr[ct];
      }
#pragma unroll
      for (int m = 1; m < 16; m <<= 1) {  // reduce 16 cols within quad
        sp += __shfl_xor(sp, m, 64);
        tp += __shfl_xor(tp, m, 64);
      }
      if (l16 == 0) {
        int row = rh * 32 + rt * 16 + q * 4 + r;
        atomicAdd(&s_l[row], sp);  // col-halves combine here
        atomicAdd(&t_l[row], tp);
      }
    }
  }
  __syncthreads();
  if (tid < 64 && nb + tid < n) {
    sbuf[nb + tid] = s_l[tid];
    tbuf[nb + tid] = t_l[tid];
  }
}

// ---------------------------------------------------------------------------
// Layer-2 via CSR gather, 16 lanes per node (coalesced col reads):
//   out[i] = mean_j s[col[j]] + b2 + t[i]
// ---------------------------------------------------------------------------
__global__ __launch_bounds__(256) void k_out(const float* __restrict__ s,
                                             const int* __restrict__ rowptr,
                                             const int* __restrict__ col,
                                             const float* __restrict__ t,
                                             const float* __restrict__ b2,
                                             float* __restrict__ out, int n) {
  int l = threadIdx.x & 15;
  int node = blockIdx.x * 16 + (threadIdx.x >> 4);
  if (node >= n) return;
  int b = rowptr[node], e = rowptr[node + 1];
  float p = 0.f;
  for (int j = b + l; j < e; j += 16) p += s[col[j]];
#pragma unroll
  for (int m = 1; m < 16; m <<= 1) p += __shfl_xor(p, m, 64);
  if (l == 0)
    out[node] = p / (float)max(e - b, 1) + b2[0] + t[node];
}

// ---------------------------------------------------------------------------

extern "C" void kernel_launch(void* const* d_in, const int* in_sizes, int n_in,
                              void* d_out, int out_size, void* d_ws,
                              size_t ws_size, hipStream_t stream) {
  const float* x   = (const float*)d_in[0];
  const int*   ei  = (const int*)d_in[1];
  const float* W1l = (const float*)d_in[2];
  const float* b1  = (const float*)d_in[3];
  const float* W1r = (const float*)d_in[4];
  const float* w2l = (const float*)d_in[5];
  const float* b2  = (const float*)d_in[6];
  const float* w2r = (const float*)d_in[7];
  float* out = (float*)d_out;

  int n = in_sizes[0] / DIM;  // 50000
  int E = in_sizes[1] / 2;    // 600000
  const int* src = ei;
  const int* dst = ei + E;

  // workspace carve-out (~16 MB)
  char* ws = (char*)d_ws;
  size_t off = 0;
  auto take = [&](size_t bytes) -> void* {
    void* p = ws + off;
    off = (off + bytes + 511) & ~(size_t)511;
    return p;
  };
  int*      deg    = (int*)take((size_t)n * 4);  // aliased as cursor
  int*      rowptr = (int*)take((size_t)(n + 1) * 4);
  int*      col    = (int*)take((size_t)E * 4);
  int*      part   = (int*)take(1024);
  _Float16* xh     = (_Float16*)take((size_t)n * DIM * 2);
  _Float16* Wt     = (_Float16*)take((size_t)DIM * 256 * 2);
  float*    sbuf   = (float*)take((size_t)n * 4);
  float*    tbuf   = (float*)take((size_t)n * 4);
  int* cursor = deg;
  (void)ws_size; (void)n_in; (void)out_size;

  hipMemsetAsync(deg, 0, (size_t)n * 4, stream);

  int eb  = (E + 255) / 256;          // 2344
  int nbk = (n + 255) / 256;          // 196 (<=256 for partial scan)
  int n4  = n * DIM / 4;              // 1,600,000
  int bx  = (n4 + 255) / 256;         // 6250
  int bw  = (DIM * 256 + 255) / 256;  // 128

  k_pre<<<bx + eb + bw, 256, 0, stream>>>(x, xh, n4, bx, dst, deg, E, eb,
                                          W1l, W1r, Wt);
  k_scan1<<<nbk, 256, 0, stream>>>(deg, part, n);
  k_scan23<<<nbk, 256, 0, stream>>>(deg, part, nbk, rowptr, cursor, n, E);
  k_fill<<<eb, 256, 0, stream>>>(src, dst, cursor, col, E);
  k_gemm<<<(n + 63) / 64, 256, 0, stream>>>(xh, rowptr, col, Wt, b1, w2l, w2r,
                                            sbuf, tbuf, n);
  k_out<<<(n + 15) / 16, 256, 0, stream>>>(sbuf, rowptr, col, tbuf, b2, out, n);
}